// Round 5
// baseline (206.755 us; speedup 1.0000x reference)
//
#include <hip/hip_runtime.h>
#include <hip/hip_bf16.h>
#include <math.h>

#define NB   64      // batch
#define NN   307     // n
#define MM   614     // 2n
#define DD   64      // d_in = d_out
#define CAP  64      // max nnz per A-row/col (observed max ~33; 64 = +12 sigma)
#define LRA  0.2f    // leaky relu slope

__device__ __forceinline__ float wave_sum(float v) {
  #pragma unroll
  for (int m = 32; m >= 1; m >>= 1) v += __shfl_xor(v, m);
  return v;
}
__device__ __forceinline__ float lrelu(float v) { return v > 0.f ? v : LRA * v; }

// ---------------- K1: adjacency lists of A (CSR + CSC), batch-independent ---
__global__ __launch_bounds__(256) void k_adj(const float* __restrict__ adj,
    int* __restrict__ arow_cnt, int* __restrict__ arow_idx,
    int* __restrict__ acol_cnt, int* __restrict__ acol_idx) {
  int tid = threadIdx.x;
  int bid = blockIdx.x;
  __shared__ int cnt;
  if (tid == 0) cnt = 0;
  __syncthreads();
  if (bid < NN) {                           // CSR row scan (coalesced)
    int r = bid;
    for (int j = tid; j < NN; j += 256)
      if (adj[(size_t)r * MM + j] > 0.f)
        arow_idx[r * CAP + atomicAdd(&cnt, 1)] = j;
    __syncthreads();
    if (tid == 0) arow_cnt[r] = cnt;
  } else {                                  // CSC col scan
    int c = bid - NN;
    for (int i = tid; i < NN; i += 256)
      if (adj[(size_t)i * MM + c] > 0.f)
        acol_idx[c * CAP + atomicAdd(&cnt, 1)] = i;
    __syncthreads();
    if (tid == 0) acol_cnt[c] = cnt;
  }
}

// ---------------- K2: one block per batch, everything in LDS ----------------
// LDS: W f32 16K + Wh bf16 78.6K + Wh1/Wh2 f32 4.8K + stats 4.8K = 104.8 KB
__global__ __launch_bounds__(1024, 1) void k_batch(
    const float* __restrict__ h, const float* __restrict__ ht,
    const float* __restrict__ W, const float* __restrict__ a,
    const int* __restrict__ arow_cnt, const int* __restrict__ arow_idx,
    const int* __restrict__ acol_cnt, const int* __restrict__ acol_idx,
    float* __restrict__ out) {
  __shared__ float          Wl[DD * DD];     // W[i][o] row-major
  __shared__ __hip_bfloat16 Whl[MM * DD];    // Wh rows, bf16
  __shared__ float          Wh1l[MM];
  __shared__ float          Wh2l[MM];
  __shared__ float4         statsl[NN];      // (Wh2[j], Wh2[n+j], 1/den_j, 1/den_nj)

  const int tid  = threadIdx.x;
  const int b    = blockIdx.x;
  const int lane = tid & 63;
  const int wv   = __builtin_amdgcn_readfirstlane(tid >> 6);   // 0..15

  // stage W (coalesced float4: 1024 threads x 16B)
  reinterpret_cast<float4*>(Wl)[tid] = reinterpret_cast<const float4*>(W)[tid];
  __syncthreads();

  const float a1 = a[lane], a2 = a[64 + lane];

  // ---- Phase 1: Wh = x@W (bf16 to LDS), Wh1 = Wh@a1, Wh2 = Wh@a2 ----
  // 16 waves x 4 rows = 64 rows/pass, 10 passes
  for (int p = 0; p < 10; p++) {
    int r0 = p * 64 + wv * 4;
    const float* xp[4];
    bool valid[4];
    #pragma unroll
    for (int j = 0; j < 4; j++) {
      int r = r0 + j;
      valid[j] = (r < MM);
      int rc = valid[j] ? r : 0;
      xp[j] = (rc < NN) ? (ht + ((size_t)b * NN + rc) * DD)
                        : (h  + ((size_t)b * NN + (rc - NN)) * DD);
    }
    float acc0 = 0.f, acc1 = 0.f, acc2 = 0.f, acc3 = 0.f;
    #pragma unroll
    for (int i = 0; i < 64; i++) {
      float w = Wl[i * 64 + lane];           // conflict-free (consecutive lanes)
      acc0 = fmaf(xp[0][i], w, acc0);        // xp[j][i]: wave-uniform scalar loads
      acc1 = fmaf(xp[1][i], w, acc1);
      acc2 = fmaf(xp[2][i], w, acc2);
      acc3 = fmaf(xp[3][i], w, acc3);
    }
    float accs[4] = {acc0, acc1, acc2, acc3};
    #pragma unroll
    for (int j = 0; j < 4; j++) {
      float p1 = wave_sum(accs[j] * a1);
      float p2 = wave_sum(accs[j] * a2);
      int r = r0 + j;
      if (valid[j]) {
        Whl[r * 64 + lane] = __float2bfloat16(accs[j]);
        if (lane == 0) { Wh1l[r] = p1; Wh2l[r] = p2; }
      }
    }
  }
  __syncthreads();

  // ---- Phase 2: column-pair softmax denominators (cols j and n+j) ----
  for (int j = wv; j < NN; j += 16) {
    int cnt = acol_cnt[j];
    float wh2j  = Wh2l[j];
    float wh2nj = Wh2l[NN + j];
    float s0 = 0.f, s1 = 0.f;
    if (lane < cnt) {
      int i = acol_idx[j * CAP + lane];
      s0 = __expf(lrelu(Wh1l[i] + wh2j));
      s1 = __expf(lrelu(Wh1l[NN + i] + wh2nj));
    }
    s0 = wave_sum(s0);
    s1 = wave_sum(s1);
    s1 += __expf(lrelu(Wh1l[j] + wh2nj));    // identity entry of column n+j
    if (lane == 0) statsl[j] = make_float4(wh2j, wh2nj, 1.f / s0, 1.f / s1);
  }
  __syncthreads();

  // ---- Phase 3: row-pair output (sparse att @ Wh from LDS), ELU, store ----
  for (int i = wv; i < NN; i += 16) {
    int rcnt = arow_cnt[i];
    float wh1a = Wh1l[i];
    float wh1b = Wh1l[NN + i];
    int j = 0;
    float w0 = 0.f, w1 = 0.f;
    if (lane < rcnt) {
      j = arow_idx[i * CAP + lane];
      float4 st = statsl[j];
      w0 = __expf(lrelu(wh1a + st.x)) * st.z;
      w1 = __expf(lrelu(wh1b + st.y)) * st.w;
    }
    float acc0a = 0.f, acc0b = 0.f, acc1a = 0.f, acc1b = 0.f;
    for (int k = 0; k + 1 < rcnt; k += 2) {
      int   jka = __shfl(j, k),   jkb = __shfl(j, k + 1);
      float w0a = __shfl(w0, k),  w0b = __shfl(w0, k + 1);
      float w1a = __shfl(w1, k),  w1b = __shfl(w1, k + 1);
      acc0a = fmaf(w0a, __bfloat162float(Whl[jka * 64 + lane]), acc0a);
      acc1a = fmaf(w1a, __bfloat162float(Whl[(NN + jka) * 64 + lane]), acc1a);
      acc0b = fmaf(w0b, __bfloat162float(Whl[jkb * 64 + lane]), acc0b);
      acc1b = fmaf(w1b, __bfloat162float(Whl[(NN + jkb) * 64 + lane]), acc1b);
    }
    if (rcnt & 1) {
      int k = rcnt - 1;
      int   jka = __shfl(j, k);
      float w0a = __shfl(w0, k), w1a = __shfl(w1, k);
      acc0a = fmaf(w0a, __bfloat162float(Whl[jka * 64 + lane]), acc0a);
      acc1a = fmaf(w1a, __bfloat162float(Whl[(NN + jka) * 64 + lane]), acc1a);
    }
    // identity entry: row i attends column n+i
    float4 sti = statsl[i];
    acc0a = fmaf(__expf(lrelu(wh1a + sti.y)) * sti.w,
                 __bfloat162float(Whl[(NN + i) * 64 + lane]), acc0a);
    float acc0 = acc0a + acc0b, acc1 = acc1a + acc1b;
    float r0 = acc0 > 0.f ? acc0 : expm1f(acc0);   // ELU
    float r1 = acc1 > 0.f ? acc1 : expm1f(acc1);
    out[((size_t)(b * NN + i)) * 128 + lane]      = r0;
    out[((size_t)(b * NN + i)) * 128 + 64 + lane] = r1;
  }
}

extern "C" void kernel_launch(void* const* d_in, const int* in_sizes, int n_in,
                              void* d_out, int out_size, void* d_ws, size_t ws_size,
                              hipStream_t stream) {
  const float* h   = (const float*)d_in[0];
  const float* ht  = (const float*)d_in[1];
  const float* W   = (const float*)d_in[2];
  const float* a   = (const float*)d_in[3];
  const float* adj = (const float*)d_in[4];
  float* out = (float*)d_out;

  char* ws = (char*)d_ws;
  size_t off = 0;
  auto alloc = [&](size_t bytes) -> void* {
    void* p = ws + off;
    off = (off + bytes + 255) & ~(size_t)255;
    return p;
  };
  int* arow_cnt = (int*)alloc(NN * 4);
  int* acol_cnt = (int*)alloc(NN * 4);
  int* arow_idx = (int*)alloc((size_t)NN * CAP * 4);
  int* acol_idx = (int*)alloc((size_t)NN * CAP * 4);

  k_adj<<<2 * NN, 256, 0, stream>>>(adj, arow_cnt, arow_idx, acol_cnt, acol_idx);
  k_batch<<<NB, 1024, 0, stream>>>(h, ht, W, a,
      arow_cnt, arow_idx, acol_cnt, acol_idx, out);
}

// Round 6
// 148.955 us; speedup vs baseline: 1.3880x; 1.3880x over previous
//
#include <hip/hip_runtime.h>
#include <hip/hip_bf16.h>
#include <math.h>

#define NB   64      // batch
#define NN   307     // n
#define MM   614     // 2n
#define DD   64      // d_in = d_out
#define CAP  64      // max nnz per A-row/col (observed max ~33; 64 = +12 sigma)
#define LRA  0.2f    // leaky relu slope
#define WHB  39      // ceil(614/16) Wh groups per batch
#define NTASK (NB * NN)  // 19648 wave-tasks

__device__ __forceinline__ float wave_sum(float v) {
  #pragma unroll
  for (int m = 32; m >= 1; m >>= 1) v += __shfl_xor(v, m);
  return v;
}
__device__ __forceinline__ float lrelu(float v) { return v > 0.f ? v : LRA * v; }

// ---------------- K1: fused {A-row build | A-col build | Wh GEMV} -----------
__global__ __launch_bounds__(256) void k_prep(const float* __restrict__ h,
    const float* __restrict__ ht, const float* __restrict__ W,
    const float* __restrict__ a, const float* __restrict__ adj,
    int* __restrict__ arow_cnt, int* __restrict__ arow_idx,
    int* __restrict__ acol_cnt, int* __restrict__ acol_idx,
    float* __restrict__ Wh, float* __restrict__ Wh1, float* __restrict__ Wh2) {
  int tid = threadIdx.x;
  int bid = blockIdx.x;

  if (bid < 2 * NN) {                       // ---- adjacency build roles ----
    __shared__ int cnt;
    if (tid == 0) cnt = 0;
    __syncthreads();
    if (bid < NN) {                         // CSR row scan (coalesced)
      int r = bid;
      for (int j = tid; j < NN; j += 256)
        if (adj[(size_t)r * MM + j] > 0.f)
          arow_idx[r * CAP + atomicAdd(&cnt, 1)] = j;
      __syncthreads();
      if (tid == 0) arow_cnt[r] = cnt;
    } else {                                // CSC col scan
      int c = bid - NN;
      for (int i = tid; i < NN; i += 256)
        if (adj[(size_t)i * MM + c] > 0.f)
          acol_idx[c * CAP + atomicAdd(&cnt, 1)] = i;
      __syncthreads();
      if (tid == 0) acol_cnt[c] = cnt;
    }
    return;
  }

  // ---- Wh GEMV role: 4 waves/block, 4 rows/wave ----
  // lane l loads x[r][l] coalesced; inner loop broadcasts via __shfl.
  __shared__ float Wl[DD * DD];             // W[i][o] row-major, 16 KB
  #pragma unroll
  for (int k = 0; k < 16; k++) Wl[tid + k * 256] = W[tid + k * 256];
  __syncthreads();

  int lane = tid & 63;
  int wv   = __builtin_amdgcn_readfirstlane(tid >> 6);
  int blk  = bid - 2 * NN;
  int b    = blk / WHB;
  int r0   = (blk % WHB) * 16 + wv * 4;

  float xv[4];
  bool valid[4];
  #pragma unroll
  for (int j = 0; j < 4; j++) {
    int r = r0 + j;
    valid[j] = (r < MM);
    int rc = valid[j] ? r : 0;
    const float* xp = (rc < NN) ? (ht + ((size_t)b * NN + rc) * DD)
                                : (h  + ((size_t)b * NN + (rc - NN)) * DD);
    xv[j] = xp[lane];                       // coalesced vector load
  }

  float a1 = a[lane], a2 = a[64 + lane];
  float acc0 = 0.f, acc1 = 0.f, acc2 = 0.f, acc3 = 0.f;
  #pragma unroll
  for (int i = 0; i < 64; i++) {
    float w = Wl[i * 64 + lane];            // conflict-free b32
    acc0 = fmaf(__shfl(xv[0], i), w, acc0);
    acc1 = fmaf(__shfl(xv[1], i), w, acc1);
    acc2 = fmaf(__shfl(xv[2], i), w, acc2);
    acc3 = fmaf(__shfl(xv[3], i), w, acc3);
  }

  float accs[4] = {acc0, acc1, acc2, acc3};
  #pragma unroll
  for (int j = 0; j < 4; j++) {
    float p1 = wave_sum(accs[j] * a1);
    float p2 = wave_sum(accs[j] * a2);
    int r = r0 + j;
    if (valid[j]) {
      Wh[((size_t)(b * MM + r)) * DD + lane] = accs[j];
      if (lane == 0) { Wh1[b * MM + r] = p1; Wh2[b * MM + r] = p2; }
    }
  }
}

// ---------------- K2: column-pair softmax denominators (single pass) --------
__global__ __launch_bounds__(256) void k_stats(const float* __restrict__ Wh1,
    const float* __restrict__ Wh2, const int* __restrict__ acol_cnt,
    const int* __restrict__ acol_idx, float4* __restrict__ stats) {
  int lane = threadIdx.x & 63;
  int task = blockIdx.x * 4 + (threadIdx.x >> 6);
  int b = task / NN, j = task - b * NN;
  const float* wh1 = Wh1 + (size_t)b * MM;
  float wh2j  = Wh2[(size_t)b * MM + j];
  float wh2nj = Wh2[(size_t)b * MM + NN + j];
  int cnt = acol_cnt[j];
  float s0 = 0.f, s1 = 0.f;
  if (lane < cnt) {
    int i = acol_idx[j * CAP + lane];
    s0 = __expf(lrelu(wh1[i] + wh2j));
    s1 = __expf(lrelu(wh1[NN + i] + wh2nj));
  }
  s0 = wave_sum(s0);
  s1 = wave_sum(s1);
  s1 += __expf(lrelu(wh1[j] + wh2nj));     // identity entry of column n+j
  if (lane == 0) stats[task] = make_float4(wh2j, wh2nj, 1.f / s0, 1.f / s1);
}

// ---------------- K3: row-pair output (sparse att @ Wh), ELU, store ---------
__global__ __launch_bounds__(256) void k_out(const float* __restrict__ Wh,
    const float* __restrict__ Wh1, const float4* __restrict__ stats,
    const int* __restrict__ arow_cnt, const int* __restrict__ arow_idx,
    float* __restrict__ out) {
  int lane = threadIdx.x & 63;
  int bid = blockIdx.x;
  int sb = (bid & 7) * 614 + (bid >> 3);   // XCD swizzle: 4912 = 8*614
  int task = sb * 4 + (threadIdx.x >> 6);
  int b = task / NN, i = task - b * NN;
  const float* whB = Wh + (size_t)b * MM * DD;
  float wh1a = Wh1[(size_t)b * MM + i];
  float wh1b = Wh1[(size_t)b * MM + NN + i];
  int rcnt = arow_cnt[i];
  int j = 0;
  float w0 = 0.f, w1 = 0.f;
  if (lane < rcnt) {
    j = arow_idx[i * CAP + lane];
    float4 st = stats[(size_t)b * NN + j];
    w0 = __expf(lrelu(wh1a + st.x)) * st.z;
    w1 = __expf(lrelu(wh1b + st.y)) * st.w;
  }
  float acc0a = 0.f, acc0b = 0.f, acc1a = 0.f, acc1b = 0.f;
  for (int k = 0; k + 1 < rcnt; k += 2) {
    int   jka = __shfl(j, k),   jkb = __shfl(j, k + 1);
    float w0a = __shfl(w0, k),  w0b = __shfl(w0, k + 1);
    float w1a = __shfl(w1, k),  w1b = __shfl(w1, k + 1);
    const float* pa = whB + (size_t)jka * DD + lane;
    const float* pb = whB + (size_t)jkb * DD + lane;
    acc0a = fmaf(w0a, pa[0], acc0a);
    acc1a = fmaf(w1a, pa[NN * DD], acc1a);
    acc0b = fmaf(w0b, pb[0], acc0b);
    acc1b = fmaf(w1b, pb[NN * DD], acc1b);
  }
  if (rcnt & 1) {
    int k = rcnt - 1;
    int   jka = __shfl(j, k);
    float w0a = __shfl(w0, k), w1a = __shfl(w1, k);
    const float* pa = whB + (size_t)jka * DD + lane;
    acc0a = fmaf(w0a, pa[0], acc0a);
    acc1a = fmaf(w1a, pa[NN * DD], acc1a);
  }
  // identity entry: row i attends column n+i
  float4 sti = stats[(size_t)b * NN + i];
  acc0a = fmaf(__expf(lrelu(wh1a + sti.y)) * sti.w,
               whB[(size_t)(NN + i) * DD + lane], acc0a);
  float acc0 = acc0a + acc0b, acc1 = acc1a + acc1b;
  float r0 = acc0 > 0.f ? acc0 : expm1f(acc0);   // ELU
  float r1 = acc1 > 0.f ? acc1 : expm1f(acc1);
  out[((size_t)(b * NN + i)) * 128 + lane]      = r0;
  out[((size_t)(b * NN + i)) * 128 + 64 + lane] = r1;
}

extern "C" void kernel_launch(void* const* d_in, const int* in_sizes, int n_in,
                              void* d_out, int out_size, void* d_ws, size_t ws_size,
                              hipStream_t stream) {
  const float* h   = (const float*)d_in[0];
  const float* ht  = (const float*)d_in[1];
  const float* W   = (const float*)d_in[2];
  const float* a   = (const float*)d_in[3];
  const float* adj = (const float*)d_in[4];
  float* out = (float*)d_out;

  char* ws = (char*)d_ws;
  size_t off = 0;
  auto alloc = [&](size_t bytes) -> void* {
    void* p = ws + off;
    off = (off + bytes + 255) & ~(size_t)255;
    return p;
  };
  float*  Wh       = (float*)alloc((size_t)NB * MM * DD * 4);
  float4* stats    = (float4*)alloc((size_t)NB * NN * 16);
  float*  Wh1      = (float*)alloc((size_t)NB * MM * 4);
  float*  Wh2      = (float*)alloc((size_t)NB * MM * 4);
  int*    arow_cnt = (int*)alloc(NN * 4);
  int*    acol_cnt = (int*)alloc(NN * 4);
  int*    arow_idx = (int*)alloc((size_t)NN * CAP * 4);
  int*    acol_idx = (int*)alloc((size_t)NN * CAP * 4);

  k_prep<<<2 * NN + NB * WHB, 256, 0, stream>>>(h, ht, W, a, adj,
      arow_cnt, arow_idx, acol_cnt, acol_idx, Wh, Wh1, Wh2);
  k_stats<<<NTASK / 4, 256, 0, stream>>>(Wh1, Wh2, acol_cnt, acol_idx, stats);
  k_out<<<NTASK / 4, 256, 0, stream>>>(Wh, Wh1, stats, arow_cnt, arow_idx, out);
}